// Round 11
// baseline (405.083 us; speedup 1.0000x reference)
//
#include <hip/hip_runtime.h>

#define NN 50000
#define EE 800000
#define FIN 128
#define DD 64
#define RR 8
#define LL 3

#define ND (NN*DD)      // 3,200,000
#define NR (NN*RR)      // 400,000

#define SB 1024
#define NSB ((NR + SB - 1) / SB)   // 391
#define ECAP 1024       // per-block edge-list cache (32 dst x 8 rel, mean 512)
#define ASF 68          // LDS A-tile row stride in floats (bank-spread)
#define KB 576          // K total per layer GEMM (8 rel + root) * 64

typedef __attribute__((ext_vector_type(8))) short bf16x8;
typedef __attribute__((ext_vector_type(4))) float f32x4;
typedef _Float16 half_t;

__device__ __forceinline__ unsigned short f2bf(float x) {
  unsigned u = __float_as_uint(x);
  u += 0x7fff + ((u >> 16) & 1);           // round-to-nearest-even
  return (unsigned short)(u >> 16);
}
__device__ __forceinline__ void split_bf(float x, short& h, short& l) {
  unsigned short hu = f2bf(x);
  float hf = __uint_as_float((unsigned)hu << 16);
  h = (short)hu;
  l = (short)f2bf(x - hf);
}
__device__ __forceinline__ float h2f_bits(unsigned u) {
  unsigned short rw = (unsigned short)u;
  _Float16 hv;
  __builtin_memcpy(&hv, &rw, 2);
  return (float)hv;
}

// ---- precompute bf16 hi/lo transposed weights (W_rel/W_root and W_in) ------
__global__ void k_prep(const float* __restrict__ W_rel,
                       const float* __restrict__ W_root,
                       const float* __restrict__ W_in,
                       short* __restrict__ Btp, short* __restrict__ Wt) {
  const int idx = blockIdx.x * 256 + threadIdx.x;
  if (idx < LL * DD * KB) {
    const int k = idx % KB, n = (idx / KB) % DD, l = idx / (KB * DD);
    float w;
    if (k < 512) w = W_rel[(((size_t)l*RR + (k >> 6))*DD + (k & 63))*DD + n];
    else         w = W_root[((size_t)l*DD + (k - 512))*DD + n];
    short hi, lo; split_bf(w, hi, lo);
    Btp[((size_t)(l*2+0)*DD + n)*KB + k] = hi;
    Btp[((size_t)(l*2+1)*DD + n)*KB + k] = lo;
  }
  if (idx < DD * FIN) {
    const int k = idx % FIN, n = idx / FIN;
    float w = W_in[(size_t)k*DD + n];
    short hi, lo; split_bf(w, hi, lo);
    Wt[((size_t)0*DD + n)*FIN + k] = hi;
    Wt[((size_t)1*DD + n)*FIN + k] = lo;
  }
}

// ---- input projection: h = relu(x @ W_in + b_in), stored fp16 --------------
__global__ __launch_bounds__(256) void k_input_mfma(
    const float* __restrict__ x, const short* __restrict__ Wt,
    const float* __restrict__ b, half_t* __restrict__ h) {
  __shared__ short Ah[DD * 136];   // 64 rows x K=128, stride 136
  __shared__ short Al[DD * 136];
  const int t = threadIdx.x;
  const int lane = t & 63, wv = t >> 6;
  const int lr = lane & 15, lc = lane >> 4;
  const int n0 = blockIdx.x * 64;

  { // stage x rows as hi/lo bf16
    const int row = t >> 2, cb = (t & 3) * 32;
    const int n = n0 + row;
    #pragma unroll
    for (int i = 0; i < 8; ++i) {
      const int col = cb + i * 4;
      float4 v = make_float4(0.f,0.f,0.f,0.f);
      if (n < NN) v = *(const float4*)(x + (size_t)n*FIN + col);
      short h0,l0,h1,l1,h2,l2,h3,l3;
      split_bf(v.x,h0,l0); split_bf(v.y,h1,l1);
      split_bf(v.z,h2,l2); split_bf(v.w,h3,l3);
      unsigned long long ph = (unsigned short)h0 | ((unsigned long long)(unsigned short)h1<<16)
          | ((unsigned long long)(unsigned short)h2<<32) | ((unsigned long long)(unsigned short)h3<<48);
      unsigned long long pl = (unsigned short)l0 | ((unsigned long long)(unsigned short)l1<<16)
          | ((unsigned long long)(unsigned short)l2<<32) | ((unsigned long long)(unsigned short)l3<<48);
      *(unsigned long long*)&Ah[row*136 + col] = ph;
      *(unsigned long long*)&Al[row*136 + col] = pl;
    }
  }
  __syncthreads();

  const int m0 = wv * 16;
  f32x4 acc[4];
  #pragma unroll
  for (int nt = 0; nt < 4; ++nt) acc[nt] = (f32x4){0.f,0.f,0.f,0.f};
  const int aoff = (m0 + lr)*136 + lc*8;
  int boff[4];
  #pragma unroll
  for (int nt = 0; nt < 4; ++nt) boff[nt] = (nt*16 + lr)*FIN + lc*8;

  #pragma unroll
  for (int ks = 0; ks < 4; ++ks) {
    const bf16x8 ah = *(const bf16x8*)&Ah[aoff + ks*32];
    const bf16x8 al = *(const bf16x8*)&Al[aoff + ks*32];
    #pragma unroll
    for (int nt = 0; nt < 4; ++nt) {
      const bf16x8 bh = *(const bf16x8*)(Wt + boff[nt] + ks*32);
      const bf16x8 bl = *(const bf16x8*)(Wt + DD*FIN + boff[nt] + ks*32);
      acc[nt] = __builtin_amdgcn_mfma_f32_16x16x32_bf16(ah, bh, acc[nt], 0, 0, 0);
      acc[nt] = __builtin_amdgcn_mfma_f32_16x16x32_bf16(al, bh, acc[nt], 0, 0, 0);
      acc[nt] = __builtin_amdgcn_mfma_f32_16x16x32_bf16(ah, bl, acc[nt], 0, 0, 0);
    }
  }
  #pragma unroll
  for (int nt = 0; nt < 4; ++nt) {
    const float bb = b[nt*16 + lr];
    #pragma unroll
    for (int i = 0; i < 4; ++i) {
      const int m = n0 + m0 + lc*4 + i;
      if (m < NN) h[(size_t)m*DD + nt*16 + lr] = (half_t)fmaxf(acc[nt][i] + bb, 0.f);
    }
  }
}

// ---------------- CSR build keyed by (et * NN + dst) ------------------------
__global__ void k_hist(const int* __restrict__ ei, const float* __restrict__ ea,
                       int* __restrict__ rp, float* __restrict__ outd) {
  const int e = blockIdx.x * 256 + threadIdx.x;
  if (e >= EE) return;
  const float2 v = *(const float2*)(ea + 2*e);
  outd[e] = v.x;
  atomicAdd(&rp[(int)v.y * NN + ei[EE + e]], 1);
}

__global__ __launch_bounds__(256) void k_scan1(int* __restrict__ rp,
                                               int* __restrict__ part) {
  __shared__ int ls[256];
  const int t = threadIdx.x;
  const int base = blockIdx.x * SB + t * 4;
  int v[4] = {0,0,0,0};
  #pragma unroll
  for (int i = 0; i < 4; ++i)
    if (base + i < NR) v[i] = rp[base + i];
  const int tsum = v[0] + v[1] + v[2] + v[3];
  ls[t] = tsum; __syncthreads();
  #pragma unroll
  for (int off = 1; off < 256; off <<= 1) {
    int x = (t >= off) ? ls[t - off] : 0;
    __syncthreads();
    ls[t] += x;
    __syncthreads();
  }
  if (t == 255) part[blockIdx.x] = ls[255];
  int run = ls[t] - tsum;
  #pragma unroll
  for (int i = 0; i < 4; ++i) {
    if (base + i < NR) rp[base + i] = run;
    run += v[i];
  }
}

__global__ __launch_bounds__(512) void k_scan2(int* __restrict__ part) {
  __shared__ int ls[512];
  const int t = threadIdx.x;
  const int v = (t < NSB) ? part[t] : 0;
  ls[t] = v; __syncthreads();
  #pragma unroll
  for (int off = 1; off < 512; off <<= 1) {
    int x = (t >= off) ? ls[t - off] : 0;
    __syncthreads();
    ls[t] += x;
    __syncthreads();
  }
  if (t < NSB) part[t] = ls[t] - v;
}

__global__ __launch_bounds__(256) void k_scan3(int* __restrict__ rp,
                                               const int* __restrict__ part,
                                               int* __restrict__ fill) {
  const int base = blockIdx.x * SB + threadIdx.x * 4;
  const int off = part[blockIdx.x];
  #pragma unroll
  for (int i = 0; i < 4; ++i)
    if (base + i < NR) {
      const int r = rp[base + i] + off;
      rp[base + i] = r;
      fill[base + i] = r;
    }
  if (blockIdx.x == 0 && threadIdx.x == 0) rp[NR] = EE;
}

__global__ void k_reorder(const int* __restrict__ ei, const float* __restrict__ ea,
                          int* __restrict__ fill, unsigned short* __restrict__ eidx) {
  const int e = blockIdx.x * 256 + threadIdx.x;
  if (e >= EE) return;
  const int key = (int)ea[2*e + 1] * NN + ei[EE + e];
  const int pos = atomicAdd(&fill[key], 1);
  eidx[pos] = (unsigned short)ei[e];
}

// ---------------- fused per-layer kernel -------------------------------------
// R7/R10 structure (K-split waves, fp16 carrier, no main-loop barriers).
// FIX for the 730cy/edge serial-load chain: after issuing a 16-load batch
// (zero-extended ushort loads -> 16 independent dword dests), an asm volatile
// reads ALL 16 results as simultaneous "v" operands. The register allocator
// must then keep 16 overlapping live ranges -> the 16 global loads issue
// back-to-back with ONE batch wait, instead of the pressure-minimizing
// load;use;load;use serialization (VGPR stuck at 56, R3-R10 invariant).
#define PIN16(v) asm volatile("" :: \
    "v"(v[0]),"v"(v[1]),"v"(v[2]),"v"(v[3]),"v"(v[4]),"v"(v[5]),"v"(v[6]),"v"(v[7]), \
    "v"(v[8]),"v"(v[9]),"v"(v[10]),"v"(v[11]),"v"(v[12]),"v"(v[13]),"v"(v[14]),"v"(v[15]))
#define PIN8(v) asm volatile("" :: \
    "v"(v[0]),"v"(v[1]),"v"(v[2]),"v"(v[3]),"v"(v[4]),"v"(v[5]),"v"(v[6]),"v"(v[7]))

template<bool LAST>
__global__ __launch_bounds__(256, 4) void k_layer(
    const half_t* __restrict__ h, const unsigned short* __restrict__ eidx,
    const int* __restrict__ rp, const short* __restrict__ Btp,
    const float* __restrict__ bias, void* __restrict__ outp) {
  __shared__ float Af[4][16 * ASF];        // 17,408 B
  __shared__ unsigned short els[ECAP];     //  2,048 B
  __shared__ int rpls[RR][33];             //  1,056 B
  __shared__ int baseL[RR + 1];

  const int t = threadIdx.x;
  const int lane = t & 63, wv = t >> 6;
  const int pair = wv >> 1, half = wv & 1;
  const int lr = lane & 15, lc = lane >> 4;
  const int n0 = blockIdx.x * 32;
  const int j0 = pair * 16;                // local dst-row base of this wave
  const half_t* hl = h + lane;

  for (int i = t; i < RR * 33; i += 256) {
    const int kk = i / 33, j = i - kk * 33;
    int g = n0 + j; if (g > NN) g = NN;
    rpls[kk][j] = rp[kk * NN + g];
  }
  __syncthreads();
  if (t == 0) {
    int s = 0;
    #pragma unroll
    for (int k = 0; k < RR; ++k) { baseL[k] = s; s += rpls[k][32] - rpls[k][0]; }
    baseL[RR] = s;
  }
  __syncthreads();
  const bool fit = baseL[RR] <= ECAP;
  if (fit) {
    for (int k = 0; k < RR; ++k) {
      const int g0 = rpls[k][0], sp = rpls[k][32] - g0, b0 = baseL[k];
      for (int i = t; i < sp; i += 256) els[b0 + i] = eidx[g0 + i];
    }
  }
  __syncthreads();

  float* Aw = Af[wv];                      // this wave's private staging

  auto gather = [&](int kk) {              // proven scan + batch-pinned loads
    const int ebeg = rpls[kk][j0], eend = rpls[kk][j0 + 16];
    int j = j0;
    int nxt = rpls[kk][j0 + 1];
    float acc = 0.f;
    auto flush = [&]() {
      const int cnt = nxt - rpls[kk][j];
      float m = (cnt > 1) ? acc * (1.0f / (float)cnt) : acc;
      Aw[(j - j0) * ASF + lane] = m;
    };
    auto proc = [&](float v, int e2) {
      while (e2 >= nxt) { flush(); acc = 0.f; ++j; nxt = rpls[kk][j + 1]; }
      acc += v;
    };
    auto scan = [&](auto srcAt) {
      int e = ebeg;
      for (; e + 15 < eend; e += 16) {
        int s[16]; unsigned v[16];
        #pragma unroll
        for (int i = 0; i < 16; ++i) s[i] = srcAt(e + i);
        #pragma unroll
        for (int i = 0; i < 16; ++i)
          v[i] = *(const unsigned short*)(hl + (size_t)s[i] * DD);
        PIN16(v);                          // force 16 overlapping live ranges
        #pragma unroll
        for (int i = 0; i < 16; ++i) proc(h2f_bits(v[i]), e + i);
      }
      if (e + 7 < eend) {
        int s[8]; unsigned v[8];
        #pragma unroll
        for (int i = 0; i < 8; ++i) s[i] = srcAt(e + i);
        #pragma unroll
        for (int i = 0; i < 8; ++i)
          v[i] = *(const unsigned short*)(hl + (size_t)s[i] * DD);
        PIN8(v);
        #pragma unroll
        for (int i = 0; i < 8; ++i) proc(h2f_bits(v[i]), e + i);
        e += 8;
      }
      for (; e < eend; ++e) proc((float)hl[(size_t)srcAt(e) * DD], e);
    };
    if (fit) {
      const int lb2 = baseL[kk] - rpls[kk][0];
      scan([&](int e) { return (int)els[lb2 + e]; });
    } else {
      scan([&](int e) { return (int)eidx[e]; });
    }
    while (true) {                       // flush current + remaining nodes
      flush();
      acc = 0.f; ++j;
      if (j >= j0 + 16) break;
      nxt = rpls[kk][j + 1];
    }
  };
  auto root_stage = [&]() {
    for (int jj = 0; jj < 16; jj += 4) {
      float v[4];
      #pragma unroll
      for (int i = 0; i < 4; ++i) {
        const int n = n0 + j0 + jj + i;
        v[i] = (n < NN) ? (float)h[(size_t)n * DD + lane] : 0.f;
      }
      #pragma unroll
      for (int i = 0; i < 4; ++i) Aw[(jj + i) * ASF + lane] = v[i];
    }
  };

  f32x4 acc4[4];
  #pragma unroll
  for (int nt = 0; nt < 4; ++nt) acc4[nt] = (f32x4){0.f,0.f,0.f,0.f};
  int boff[4];
  #pragma unroll
  for (int nt = 0; nt < 4; ++nt) boff[nt] = (nt*16 + lr)*KB + lc*8;
  const short* Blo = Btp + (size_t)DD * KB;
  const float* arow = Aw + lr * ASF + lc * 8;

  auto mfma_slice = [&](int koff) {
    #pragma unroll
    for (int ks = 0; ks < 2; ++ks) {
      const f32x4 a0 = *(const f32x4*)(arow + ks*32);
      const f32x4 a1 = *(const f32x4*)(arow + ks*32 + 4);
      bf16x8 ah, al;
      #pragma unroll
      for (int i = 0; i < 4; ++i) {
        short hb, lb;
        split_bf(a0[i], hb, lb); ah[i] = hb;     al[i] = lb;
        split_bf(a1[i], hb, lb); ah[4 + i] = hb; al[4 + i] = lb;
      }
      #pragma unroll
      for (int nt = 0; nt < 4; ++nt) {
        const bf16x8 bh = *(const bf16x8*)(Btp + boff[nt] + koff + ks*32);
        const bf16x8 bl = *(const bf16x8*)(Blo + boff[nt] + koff + ks*32);
        acc4[nt] = __builtin_amdgcn_mfma_f32_16x16x32_bf16(ah, bh, acc4[nt], 0, 0, 0);
        acc4[nt] = __builtin_amdgcn_mfma_f32_16x16x32_bf16(al, bh, acc4[nt], 0, 0, 0);
        acc4[nt] = __builtin_amdgcn_mfma_f32_16x16x32_bf16(ah, bl, acc4[nt], 0, 0, 0);
      }
    }
  };

  // main loop: 4 relations for this K-half; no barriers (private buffers)
  #pragma unroll 1
  for (int kx = 0; kx < 4; ++kx) {
    const int kk = half * 4 + kx;
    gather(kk);
    mfma_slice(kk * 64);
  }
  if (!half) {            // half 0 also handles the root term (K 512..575)
    root_stage();
    mfma_slice(512);
  } else {                // half 1 publishes its partial C into its buffer
    #pragma unroll
    for (int nt = 0; nt < 4; ++nt)
      #pragma unroll
      for (int i = 0; i < 4; ++i)
        Aw[(lc*4 + i) * ASF + nt*16 + lr] = acc4[nt][i];
  }
  __syncthreads();        // partials visible
  if (!half) {
    const float* Pw = Af[wv + 1];
    #pragma unroll
    for (int nt = 0; nt < 4; ++nt) {
      const float bb = bias[nt*16 + lr];
      #pragma unroll
      for (int i = 0; i < 4; ++i) {
        const int m = n0 + j0 + lc*4 + i;
        if (m < NN) {
          const float r =
              fmaxf(acc4[nt][i] + Pw[(lc*4 + i) * ASF + nt*16 + lr] + bb, 0.f);
          const size_t idx = (size_t)m*DD + nt*16 + lr;
          if (LAST) ((float*)outp)[idx] = r;
          else      ((half_t*)outp)[idx] = (half_t)r;
        }
      }
    }
  }
}

extern "C" void kernel_launch(void* const* d_in, const int* in_sizes, int n_in,
                              void* d_out, int out_size, void* d_ws, size_t ws_size,
                              hipStream_t stream) {
  const float* x      = (const float*)d_in[0];
  const int*   ei     = (const int*)d_in[1];
  const float* ea     = (const float*)d_in[2];
  const float* W_in   = (const float*)d_in[3];
  const float* b_in   = (const float*)d_in[4];
  const float* W_rel  = (const float*)d_in[5];
  const float* W_root = (const float*)d_in[6];
  const float* b_conv = (const float*)d_in[7];
  float* out = (float*)d_out;

  // ws layout (offsets unchanged; hA/hB fp16, use half the space)
  char* ws = (char*)d_ws;
  half_t*         hA   = (half_t*)(ws);                      // 6,400,000 used
  half_t*         hB   = (half_t*)(ws + 12800000);           // 6,400,000 used
  int*            rp   = (int*)  (ws + 25600000);            // 1,600,256
  int*            fill = (int*)  (ws + 27200256);            // 1,600,000
  unsigned short* eidx = (unsigned short*)(ws + 28800256);   // 1,600,000
  int*            part = (int*)  (ws + 30400256);            // 2,048
  short*          Btp  = (short*)(ws + 30402304);            // 442,368
  short*          Wt   = (short*)(ws + 30844672);            // 32,768

  k_prep<<<(LL*DD*KB + 255)/256, 256, 0, stream>>>(W_rel, W_root, W_in, Btp, Wt);
  k_input_mfma<<<(NN + 63)/64, 256, 0, stream>>>(x, Wt, b_in, hA);

  // CSR keyed (et, dst) — built once, reused by all 3 layers
  hipMemsetAsync(rp, 0, (size_t)NR*4, stream);
  k_hist<<<(EE + 255)/256, 256, 0, stream>>>(ei, ea, rp, out + (size_t)ND);
  k_scan1<<<NSB, 256, 0, stream>>>(rp, part);
  k_scan2<<<1, 512, 0, stream>>>(part);
  k_scan3<<<NSB, 256, 0, stream>>>(rp, part, fill);
  k_reorder<<<(EE + 255)/256, 256, 0, stream>>>(ei, ea, fill, eidx);

  const int NBL = (NN + 31) / 32;   // 1563
  k_layer<false><<<NBL, 256, 0, stream>>>(hA, eidx, rp,
      Btp + (size_t)0*2*DD*KB, b_conv + (size_t)0*DD, hB);
  k_layer<false><<<NBL, 256, 0, stream>>>(hB, eidx, rp,
      Btp + (size_t)1*2*DD*KB, b_conv + (size_t)1*DD, hA);
  k_layer<true><<<NBL, 256, 0, stream>>>(hA, eidx, rp,
      Btp + (size_t)2*2*DD*KB, b_conv + (size_t)2*DD, out);
}

// Round 12
// 400.249 us; speedup vs baseline: 1.0121x; 1.0121x over previous
//
#include <hip/hip_runtime.h>

#define NN 50000
#define EE 800000
#define FIN 128
#define DD 64
#define RR 8
#define LL 3

#define ND (NN*DD)      // 3,200,000
#define NR (NN*RR)      // 400,000

#define SB 1024
#define NSB ((NR + SB - 1) / SB)   // 391
#define ECAP 1024       // per-block edge-list cache (32 dst x 8 rel, mean 512)
#define ASF 68          // LDS A-tile row stride in floats (bank-spread)
#define KB 576          // K total per layer GEMM (8 rel + root) * 64

typedef __attribute__((ext_vector_type(8))) short bf16x8;
typedef __attribute__((ext_vector_type(4))) float f32x4;
typedef _Float16 half_t;

__device__ __forceinline__ unsigned short f2bf(float x) {
  unsigned u = __float_as_uint(x);
  u += 0x7fff + ((u >> 16) & 1);           // round-to-nearest-even
  return (unsigned short)(u >> 16);
}
__device__ __forceinline__ void split_bf(float x, short& h, short& l) {
  unsigned short hu = f2bf(x);
  float hf = __uint_as_float((unsigned)hu << 16);
  h = (short)hu;
  l = (short)f2bf(x - hf);
}
__device__ __forceinline__ float h2f_bits(unsigned u) {
  unsigned short rw = (unsigned short)u;
  _Float16 hv;
  __builtin_memcpy(&hv, &rw, 2);
  return (float)hv;
}

// ---- precompute bf16 hi/lo transposed weights (W_rel/W_root and W_in) ------
__global__ void k_prep(const float* __restrict__ W_rel,
                       const float* __restrict__ W_root,
                       const float* __restrict__ W_in,
                       short* __restrict__ Btp, short* __restrict__ Wt) {
  const int idx = blockIdx.x * 256 + threadIdx.x;
  if (idx < LL * DD * KB) {
    const int k = idx % KB, n = (idx / KB) % DD, l = idx / (KB * DD);
    float w;
    if (k < 512) w = W_rel[(((size_t)l*RR + (k >> 6))*DD + (k & 63))*DD + n];
    else         w = W_root[((size_t)l*DD + (k - 512))*DD + n];
    short hi, lo; split_bf(w, hi, lo);
    Btp[((size_t)(l*2+0)*DD + n)*KB + k] = hi;
    Btp[((size_t)(l*2+1)*DD + n)*KB + k] = lo;
  }
  if (idx < DD * FIN) {
    const int k = idx % FIN, n = idx / FIN;
    float w = W_in[(size_t)k*DD + n];
    short hi, lo; split_bf(w, hi, lo);
    Wt[((size_t)0*DD + n)*FIN + k] = hi;
    Wt[((size_t)1*DD + n)*FIN + k] = lo;
  }
}

// ---- input projection: h = relu(x @ W_in + b_in), stored fp16 --------------
__global__ __launch_bounds__(256) void k_input_mfma(
    const float* __restrict__ x, const short* __restrict__ Wt,
    const float* __restrict__ b, half_t* __restrict__ h) {
  __shared__ short Ah[DD * 136];   // 64 rows x K=128, stride 136
  __shared__ short Al[DD * 136];
  const int t = threadIdx.x;
  const int lane = t & 63, wv = t >> 6;
  const int lr = lane & 15, lc = lane >> 4;
  const int n0 = blockIdx.x * 64;

  { // stage x rows as hi/lo bf16
    const int row = t >> 2, cb = (t & 3) * 32;
    const int n = n0 + row;
    #pragma unroll
    for (int i = 0; i < 8; ++i) {
      const int col = cb + i * 4;
      float4 v = make_float4(0.f,0.f,0.f,0.f);
      if (n < NN) v = *(const float4*)(x + (size_t)n*FIN + col);
      short h0,l0,h1,l1,h2,l2,h3,l3;
      split_bf(v.x,h0,l0); split_bf(v.y,h1,l1);
      split_bf(v.z,h2,l2); split_bf(v.w,h3,l3);
      unsigned long long ph = (unsigned short)h0 | ((unsigned long long)(unsigned short)h1<<16)
          | ((unsigned long long)(unsigned short)h2<<32) | ((unsigned long long)(unsigned short)h3<<48);
      unsigned long long pl = (unsigned short)l0 | ((unsigned long long)(unsigned short)l1<<16)
          | ((unsigned long long)(unsigned short)l2<<32) | ((unsigned long long)(unsigned short)l3<<48);
      *(unsigned long long*)&Ah[row*136 + col] = ph;
      *(unsigned long long*)&Al[row*136 + col] = pl;
    }
  }
  __syncthreads();

  const int m0 = wv * 16;
  f32x4 acc[4];
  #pragma unroll
  for (int nt = 0; nt < 4; ++nt) acc[nt] = (f32x4){0.f,0.f,0.f,0.f};
  const int aoff = (m0 + lr)*136 + lc*8;
  int boff[4];
  #pragma unroll
  for (int nt = 0; nt < 4; ++nt) boff[nt] = (nt*16 + lr)*FIN + lc*8;

  #pragma unroll
  for (int ks = 0; ks < 4; ++ks) {
    const bf16x8 ah = *(const bf16x8*)&Ah[aoff + ks*32];
    const bf16x8 al = *(const bf16x8*)&Al[aoff + ks*32];
    #pragma unroll
    for (int nt = 0; nt < 4; ++nt) {
      const bf16x8 bh = *(const bf16x8*)(Wt + boff[nt] + ks*32);
      const bf16x8 bl = *(const bf16x8*)(Wt + DD*FIN + boff[nt] + ks*32);
      acc[nt] = __builtin_amdgcn_mfma_f32_16x16x32_bf16(ah, bh, acc[nt], 0, 0, 0);
      acc[nt] = __builtin_amdgcn_mfma_f32_16x16x32_bf16(al, bh, acc[nt], 0, 0, 0);
      acc[nt] = __builtin_amdgcn_mfma_f32_16x16x32_bf16(ah, bl, acc[nt], 0, 0, 0);
    }
  }
  #pragma unroll
  for (int nt = 0; nt < 4; ++nt) {
    const float bb = b[nt*16 + lr];
    #pragma unroll
    for (int i = 0; i < 4; ++i) {
      const int m = n0 + m0 + lc*4 + i;
      if (m < NN) h[(size_t)m*DD + nt*16 + lr] = (half_t)fmaxf(acc[nt][i] + bb, 0.f);
    }
  }
}

// ---------------- CSR build keyed by (et * NN + dst) ------------------------
__global__ void k_hist(const int* __restrict__ ei, const float* __restrict__ ea,
                       int* __restrict__ rp, float* __restrict__ outd) {
  const int e = blockIdx.x * 256 + threadIdx.x;
  if (e >= EE) return;
  const float2 v = *(const float2*)(ea + 2*e);
  outd[e] = v.x;
  atomicAdd(&rp[(int)v.y * NN + ei[EE + e]], 1);
}

__global__ __launch_bounds__(256) void k_scan1(int* __restrict__ rp,
                                               int* __restrict__ part) {
  __shared__ int ls[256];
  const int t = threadIdx.x;
  const int base = blockIdx.x * SB + t * 4;
  int v[4] = {0,0,0,0};
  #pragma unroll
  for (int i = 0; i < 4; ++i)
    if (base + i < NR) v[i] = rp[base + i];
  const int tsum = v[0] + v[1] + v[2] + v[3];
  ls[t] = tsum; __syncthreads();
  #pragma unroll
  for (int off = 1; off < 256; off <<= 1) {
    int x = (t >= off) ? ls[t - off] : 0;
    __syncthreads();
    ls[t] += x;
    __syncthreads();
  }
  if (t == 255) part[blockIdx.x] = ls[255];
  int run = ls[t] - tsum;
  #pragma unroll
  for (int i = 0; i < 4; ++i) {
    if (base + i < NR) rp[base + i] = run;
    run += v[i];
  }
}

__global__ __launch_bounds__(512) void k_scan2(int* __restrict__ part) {
  __shared__ int ls[512];
  const int t = threadIdx.x;
  const int v = (t < NSB) ? part[t] : 0;
  ls[t] = v; __syncthreads();
  #pragma unroll
  for (int off = 1; off < 512; off <<= 1) {
    int x = (t >= off) ? ls[t - off] : 0;
    __syncthreads();
    ls[t] += x;
    __syncthreads();
  }
  if (t < NSB) part[t] = ls[t] - v;
}

__global__ __launch_bounds__(256) void k_scan3(int* __restrict__ rp,
                                               const int* __restrict__ part,
                                               int* __restrict__ fill) {
  const int base = blockIdx.x * SB + threadIdx.x * 4;
  const int off = part[blockIdx.x];
  #pragma unroll
  for (int i = 0; i < 4; ++i)
    if (base + i < NR) {
      const int r = rp[base + i] + off;
      rp[base + i] = r;
      fill[base + i] = r;
    }
  if (blockIdx.x == 0 && threadIdx.x == 0) rp[NR] = EE;
}

__global__ void k_reorder(const int* __restrict__ ei, const float* __restrict__ ea,
                          int* __restrict__ fill, unsigned short* __restrict__ eidx) {
  const int e = blockIdx.x * 256 + threadIdx.x;
  if (e >= EE) return;
  const int key = (int)ea[2*e + 1] * NN + ei[EE + e];
  const int pos = atomicAdd(&fill[key], 1);
  eidx[pos] = (unsigned short)ei[e];
}

// ---------------- fused per-layer kernel -------------------------------------
// R7 structure (K-split waves, fp16 carrier, no main-loop barriers) with the
// gather restructured to TWO EDGES PER LOAD INSTRUCTION: lanes 0-31 load the
// dword (2 channels) of edge a's row, lanes 32-63 of edge b's row (one
// cndmask on the src index). Redistribution to the per-lane channel layout is
// 2x ds_bpermute + halfword extract per pair. Cross-round evidence (R3-R11)
// shows k_layer time ~ #gather VMEM instructions; this halves them 800k->400k
// per layer with no new waits. proc/flush order identical -> same numerics.
template<bool LAST>
__global__ __launch_bounds__(256, 4) void k_layer(
    const half_t* __restrict__ h, const unsigned short* __restrict__ eidx,
    const int* __restrict__ rp, const short* __restrict__ Btp,
    const float* __restrict__ bias, void* __restrict__ outp) {
  __shared__ float Af[4][16 * ASF];        // 17,408 B
  __shared__ unsigned short els[ECAP];     //  2,048 B
  __shared__ int rpls[RR][33];             //  1,056 B
  __shared__ int baseL[RR + 1];

  const int t = threadIdx.x;
  const int lane = t & 63, wv = t >> 6;
  const int pair = wv >> 1, half = wv & 1;
  const int lr = lane & 15, lc = lane >> 4;
  const int n0 = blockIdx.x * 32;
  const int j0 = pair * 16;                // local dst-row base of this wave
  const half_t* hl = h + lane;
  const int bpa = (lane >> 1) << 2;        // bpermute idx: edge-a source lane
  const int bpb = ((lane >> 1) + 32) << 2; // bpermute idx: edge-b source lane
  const int qsh = (lane & 1) << 4;         // halfword select shift
  const int qoff = lane & 31;              // dword index within a 128B row

  for (int i = t; i < RR * 33; i += 256) {
    const int kk = i / 33, j = i - kk * 33;
    int g = n0 + j; if (g > NN) g = NN;
    rpls[kk][j] = rp[kk * NN + g];
  }
  __syncthreads();
  if (t == 0) {
    int s = 0;
    #pragma unroll
    for (int k = 0; k < RR; ++k) { baseL[k] = s; s += rpls[k][32] - rpls[k][0]; }
    baseL[RR] = s;
  }
  __syncthreads();
  const bool fit = baseL[RR] <= ECAP;
  if (fit) {
    for (int k = 0; k < RR; ++k) {
      const int g0 = rpls[k][0], sp = rpls[k][32] - g0, b0 = baseL[k];
      for (int i = t; i < sp; i += 256) els[b0 + i] = eidx[g0 + i];
    }
  }
  __syncthreads();

  float* Aw = Af[wv];                      // this wave's private staging

  auto gather = [&](int kk) {              // proven scan + paired loads
    const int ebeg = rpls[kk][j0], eend = rpls[kk][j0 + 16];
    int j = j0;
    int nxt = rpls[kk][j0 + 1];
    float acc = 0.f;
    auto flush = [&]() {
      const int cnt = nxt - rpls[kk][j];
      float m = (cnt > 1) ? acc * (1.0f / (float)cnt) : acc;
      Aw[(j - j0) * ASF + lane] = m;
    };
    auto proc = [&](float v, int e2) {
      while (e2 >= nxt) { flush(); acc = 0.f; ++j; nxt = rpls[kk][j + 1]; }
      acc += v;
    };
    // one paired batch: np pairs (2*np edges), loads then bpermute+proc
    auto pairBatch = [&](auto srcAt, int e, int np) {
      unsigned v[8];
      #pragma unroll
      for (int i = 0; i < 8; ++i) {
        if (i < np) {
          const int sa = srcAt(e + 2*i);
          const int sb = srcAt(e + 2*i + 1);
          const int ss = (lane < 32) ? sa : sb;
          v[i] = *((const unsigned*)(h + (size_t)ss * DD) + qoff);
        }
      }
      #pragma unroll
      for (int i = 0; i < 8; ++i) {
        if (i < np) {
          const unsigned av = (unsigned)__builtin_amdgcn_ds_bpermute(bpa, (int)v[i]);
          const unsigned bv = (unsigned)__builtin_amdgcn_ds_bpermute(bpb, (int)v[i]);
          proc(h2f_bits((av >> qsh) & 0xffffu), e + 2*i);
          proc(h2f_bits((bv >> qsh) & 0xffffu), e + 2*i + 1);
        }
      }
    };
    auto scan = [&](auto srcAt) {
      int e = ebeg;
      for (; e + 15 < eend; e += 16) pairBatch(srcAt, e, 8);
      if (e + 7 < eend) { pairBatch(srcAt, e, 4); e += 8; }
      if (e + 1 < eend) {                  // leftover pairs (2..6 edges)
        const int np = (eend - e) >> 1;
        pairBatch(srcAt, e, np);
        e += np * 2;
      }
      if (e < eend) proc((float)hl[(size_t)srcAt(e) * DD], e);  // odd single
    };
    if (fit) {
      const int lb2 = baseL[kk] - rpls[kk][0];
      scan([&](int e) { return (int)els[lb2 + e]; });
    } else {
      scan([&](int e) { return (int)eidx[e]; });
    }
    while (true) {                       // flush current + remaining nodes
      flush();
      acc = 0.f; ++j;
      if (j >= j0 + 16) break;
      nxt = rpls[kk][j + 1];
    }
  };
  auto root_stage = [&]() {
    for (int jj = 0; jj < 16; jj += 4) {
      float v[4];
      #pragma unroll
      for (int i = 0; i < 4; ++i) {
        const int n = n0 + j0 + jj + i;
        v[i] = (n < NN) ? (float)h[(size_t)n * DD + lane] : 0.f;
      }
      #pragma unroll
      for (int i = 0; i < 4; ++i) Aw[(jj + i) * ASF + lane] = v[i];
    }
  };

  f32x4 acc4[4];
  #pragma unroll
  for (int nt = 0; nt < 4; ++nt) acc4[nt] = (f32x4){0.f,0.f,0.f,0.f};
  int boff[4];
  #pragma unroll
  for (int nt = 0; nt < 4; ++nt) boff[nt] = (nt*16 + lr)*KB + lc*8;
  const short* Blo = Btp + (size_t)DD * KB;
  const float* arow = Aw + lr * ASF + lc * 8;

  auto mfma_slice = [&](int koff) {
    #pragma unroll
    for (int ks = 0; ks < 2; ++ks) {
      const f32x4 a0 = *(const f32x4*)(arow + ks*32);
      const f32x4 a1 = *(const f32x4*)(arow + ks*32 + 4);
      bf16x8 ah, al;
      #pragma unroll
      for (int i = 0; i < 4; ++i) {
        short hb, lb;
        split_bf(a0[i], hb, lb); ah[i] = hb;     al[i] = lb;
        split_bf(a1[i], hb, lb); ah[4 + i] = hb; al[4 + i] = lb;
      }
      #pragma unroll
      for (int nt = 0; nt < 4; ++nt) {
        const bf16x8 bh = *(const bf16x8*)(Btp + boff[nt] + koff + ks*32);
        const bf16x8 bl = *(const bf16x8*)(Blo + boff[nt] + koff + ks*32);
        acc4[nt] = __builtin_amdgcn_mfma_f32_16x16x32_bf16(ah, bh, acc4[nt], 0, 0, 0);
        acc4[nt] = __builtin_amdgcn_mfma_f32_16x16x32_bf16(al, bh, acc4[nt], 0, 0, 0);
        acc4[nt] = __builtin_amdgcn_mfma_f32_16x16x32_bf16(ah, bl, acc4[nt], 0, 0, 0);
      }
    }
  };

  // main loop: 4 relations for this K-half; no barriers (private buffers)
  #pragma unroll 1
  for (int kx = 0; kx < 4; ++kx) {
    const int kk = half * 4 + kx;
    gather(kk);
    mfma_slice(kk * 64);
  }
  if (!half) {            // half 0 also handles the root term (K 512..575)
    root_stage();
    mfma_slice(512);
  } else {                // half 1 publishes its partial C into its buffer
    #pragma unroll
    for (int nt = 0; nt < 4; ++nt)
      #pragma unroll
      for (int i = 0; i < 4; ++i)
        Aw[(lc*4 + i) * ASF + nt*16 + lr] = acc4[nt][i];
  }
  __syncthreads();        // partials visible
  if (!half) {
    const float* Pw = Af[wv + 1];
    #pragma unroll
    for (int nt = 0; nt < 4; ++nt) {
      const float bb = bias[nt*16 + lr];
      #pragma unroll
      for (int i = 0; i < 4; ++i) {
        const int m = n0 + j0 + lc*4 + i;
        if (m < NN) {
          const float r =
              fmaxf(acc4[nt][i] + Pw[(lc*4 + i) * ASF + nt*16 + lr] + bb, 0.f);
          const size_t idx = (size_t)m*DD + nt*16 + lr;
          if (LAST) ((float*)outp)[idx] = r;
          else      ((half_t*)outp)[idx] = (half_t)r;
        }
      }
    }
  }
}

extern "C" void kernel_launch(void* const* d_in, const int* in_sizes, int n_in,
                              void* d_out, int out_size, void* d_ws, size_t ws_size,
                              hipStream_t stream) {
  const float* x      = (const float*)d_in[0];
  const int*   ei     = (const int*)d_in[1];
  const float* ea     = (const float*)d_in[2];
  const float* W_in   = (const float*)d_in[3];
  const float* b_in   = (const float*)d_in[4];
  const float* W_rel  = (const float*)d_in[5];
  const float* W_root = (const float*)d_in[6];
  const float* b_conv = (const float*)d_in[7];
  float* out = (float*)d_out;

  // ws layout (offsets unchanged; hA/hB fp16, use half the space)
  char* ws = (char*)d_ws;
  half_t*         hA   = (half_t*)(ws);                      // 6,400,000 used
  half_t*         hB   = (half_t*)(ws + 12800000);           // 6,400,000 used
  int*            rp   = (int*)  (ws + 25600000);            // 1,600,256
  int*            fill = (int*)  (ws + 27200256);            // 1,600,000
  unsigned short* eidx = (unsigned short*)(ws + 28800256);   // 1,600,000
  int*            part = (int*)  (ws + 30400256);            // 2,048
  short*          Btp  = (short*)(ws + 30402304);            // 442,368
  short*          Wt   = (short*)(ws + 30844672);            // 32,768

  k_prep<<<(LL*DD*KB + 255)/256, 256, 0, stream>>>(W_rel, W_root, W_in, Btp, Wt);
  k_input_mfma<<<(NN + 63)/64, 256, 0, stream>>>(x, Wt, b_in, hA);

  // CSR keyed (et, dst) — built once, reused by all 3 layers
  hipMemsetAsync(rp, 0, (size_t)NR*4, stream);
  k_hist<<<(EE + 255)/256, 256, 0, stream>>>(ei, ea, rp, out + (size_t)ND);
  k_scan1<<<NSB, 256, 0, stream>>>(rp, part);
  k_scan2<<<1, 512, 0, stream>>>(part);
  k_scan3<<<NSB, 256, 0, stream>>>(rp, part, fill);
  k_reorder<<<(EE + 255)/256, 256, 0, stream>>>(ei, ea, fill, eidx);

  const int NBL = (NN + 31) / 32;   // 1563
  k_layer<false><<<NBL, 256, 0, stream>>>(hA, eidx, rp,
      Btp + (size_t)0*2*DD*KB, b_conv + (size_t)0*DD, hB);
  k_layer<false><<<NBL, 256, 0, stream>>>(hB, eidx, rp,
      Btp + (size_t)1*2*DD*KB, b_conv + (size_t)1*DD, hA);
  k_layer<true><<<NBL, 256, 0, stream>>>(hA, eidx, rp,
      Btp + (size_t)2*2*DD*KB, b_conv + (size_t)2*DD, out);
}

// Round 13
// 376.187 us; speedup vs baseline: 1.0768x; 1.0640x over previous
//
#include <hip/hip_runtime.h>

#define NN 50000
#define EE 800000
#define FIN 128
#define DD 64
#define RR 8
#define LL 3

#define ND (NN*DD)      // 3,200,000
#define NR (NN*RR)      // 400,000

#define SB 1024
#define NSB ((NR + SB - 1) / SB)   // 391
#define ECAP 1024       // per-block edge-list cache (32 dst x 8 rel, mean 512)
#define ASF 68          // LDS A-tile row stride in floats (bank-spread)
#define KB 576          // K total per layer GEMM (8 rel + root) * 64
#define HB ((EE + 255) / 256)          // 3125 hist blocks
#define PB ((LL*DD*KB + 255) / 256)    // 432 prep blocks
#define IB ((NN + 63) / 64)            // 782 input blocks

typedef __attribute__((ext_vector_type(8))) short bf16x8;
typedef __attribute__((ext_vector_type(4))) float f32x4;

__device__ __forceinline__ unsigned short f2bf(float x) {
  unsigned u = __float_as_uint(x);
  u += 0x7fff + ((u >> 16) & 1);           // round-to-nearest-even
  return (unsigned short)(u >> 16);
}
__device__ __forceinline__ void split_bf(float x, short& h, short& l) {
  unsigned short hu = f2bf(x);
  float hf = __uint_as_float((unsigned)hu << 16);
  h = (short)hu;
  l = (short)f2bf(x - hf);
}

// ---- fused: CSR histogram (+edge_distance output) AND weight transposition --
// blocks [0,HB): hist; blocks [HB,HB+PB): prep. Independent work, one launch.
__global__ void k_hist_prep(const int* __restrict__ ei, const float* __restrict__ ea,
                            int* __restrict__ rp, float* __restrict__ outd,
                            const float* __restrict__ W_rel,
                            const float* __restrict__ W_root,
                            const float* __restrict__ W_in,
                            short* __restrict__ Btp, short* __restrict__ Wt) {
  const int b = blockIdx.x;
  if (b < HB) {
    const int e = b * 256 + threadIdx.x;
    if (e >= EE) return;
    const float2 v = *(const float2*)(ea + 2*e);
    outd[e] = v.x;
    atomicAdd(&rp[(int)v.y * NN + ei[EE + e]], 1);
  } else {
    const int idx = (b - HB) * 256 + threadIdx.x;
    if (idx < LL * DD * KB) {
      const int k = idx % KB, n = (idx / KB) % DD, l = idx / (KB * DD);
      float w;
      if (k < 512) w = W_rel[(((size_t)l*RR + (k >> 6))*DD + (k & 63))*DD + n];
      else         w = W_root[((size_t)l*DD + (k - 512))*DD + n];
      short hi, lo; split_bf(w, hi, lo);
      Btp[((size_t)(l*2+0)*DD + n)*KB + k] = hi;
      Btp[((size_t)(l*2+1)*DD + n)*KB + k] = lo;
    }
    if (idx < DD * FIN) {
      const int k = idx % FIN, n = idx / FIN;
      float w = W_in[(size_t)k*DD + n];
      short hi, lo; split_bf(w, hi, lo);
      Wt[((size_t)0*DD + n)*FIN + k] = hi;
      Wt[((size_t)1*DD + n)*FIN + k] = lo;
    }
  }
}

// ---- fused: input projection h = relu(x @ W_in + b_in)  AND  scan1 ---------
// blocks [0,IB): input MFMA tiles; blocks [IB,IB+NSB): scan1 over rp.
__global__ __launch_bounds__(256) void k_input_scan1(
    const float* __restrict__ x, const short* __restrict__ Wt,
    const float* __restrict__ b, float* __restrict__ h,
    int* __restrict__ rp, int* __restrict__ part) {
  __shared__ short Ah[DD * 136];   // 64 rows x K=128, stride 136
  __shared__ short Al[DD * 136];
  const int t = threadIdx.x;

  if (blockIdx.x >= IB) {          // ---- scan1 body ----
    int* ls = (int*)Ah;
    const int bb = blockIdx.x - IB;
    const int base = bb * SB + t * 4;
    int v[4] = {0,0,0,0};
    #pragma unroll
    for (int i = 0; i < 4; ++i)
      if (base + i < NR) v[i] = rp[base + i];
    const int tsum = v[0] + v[1] + v[2] + v[3];
    ls[t] = tsum; __syncthreads();
    #pragma unroll
    for (int off = 1; off < 256; off <<= 1) {
      int xv = (t >= off) ? ls[t - off] : 0;
      __syncthreads();
      ls[t] += xv;
      __syncthreads();
    }
    if (t == 255) part[bb] = ls[255];
    int run = ls[t] - tsum;
    #pragma unroll
    for (int i = 0; i < 4; ++i) {
      if (base + i < NR) rp[base + i] = run;
      run += v[i];
    }
    return;
  }

  // ---- input projection body ----
  const int lane = t & 63, wv = t >> 6;
  const int lr = lane & 15, lc = lane >> 4;
  const int n0 = blockIdx.x * 64;

  { // stage x rows as hi/lo bf16
    const int row = t >> 2, cb = (t & 3) * 32;
    const int n = n0 + row;
    #pragma unroll
    for (int i = 0; i < 8; ++i) {
      const int col = cb + i * 4;
      float4 v = make_float4(0.f,0.f,0.f,0.f);
      if (n < NN) v = *(const float4*)(x + (size_t)n*FIN + col);
      short h0,l0,h1,l1,h2,l2,h3,l3;
      split_bf(v.x,h0,l0); split_bf(v.y,h1,l1);
      split_bf(v.z,h2,l2); split_bf(v.w,h3,l3);
      unsigned long long ph = (unsigned short)h0 | ((unsigned long long)(unsigned short)h1<<16)
          | ((unsigned long long)(unsigned short)h2<<32) | ((unsigned long long)(unsigned short)h3<<48);
      unsigned long long pl = (unsigned short)l0 | ((unsigned long long)(unsigned short)l1<<16)
          | ((unsigned long long)(unsigned short)l2<<32) | ((unsigned long long)(unsigned short)l3<<48);
      *(unsigned long long*)&Ah[row*136 + col] = ph;
      *(unsigned long long*)&Al[row*136 + col] = pl;
    }
  }
  __syncthreads();

  const int m0 = wv * 16;
  f32x4 acc[4];
  #pragma unroll
  for (int nt = 0; nt < 4; ++nt) acc[nt] = (f32x4){0.f,0.f,0.f,0.f};
  const int aoff = (m0 + lr)*136 + lc*8;
  int boff[4];
  #pragma unroll
  for (int nt = 0; nt < 4; ++nt) boff[nt] = (nt*16 + lr)*FIN + lc*8;

  #pragma unroll
  for (int ks = 0; ks < 4; ++ks) {
    const bf16x8 ah = *(const bf16x8*)&Ah[aoff + ks*32];
    const bf16x8 al = *(const bf16x8*)&Al[aoff + ks*32];
    #pragma unroll
    for (int nt = 0; nt < 4; ++nt) {
      const bf16x8 bh = *(const bf16x8*)(Wt + boff[nt] + ks*32);
      const bf16x8 bl = *(const bf16x8*)(Wt + DD*FIN + boff[nt] + ks*32);
      acc[nt] = __builtin_amdgcn_mfma_f32_16x16x32_bf16(ah, bh, acc[nt], 0, 0, 0);
      acc[nt] = __builtin_amdgcn_mfma_f32_16x16x32_bf16(al, bh, acc[nt], 0, 0, 0);
      acc[nt] = __builtin_amdgcn_mfma_f32_16x16x32_bf16(ah, bl, acc[nt], 0, 0, 0);
    }
  }
  #pragma unroll
  for (int nt = 0; nt < 4; ++nt) {
    const float bb = b[nt*16 + lr];
    #pragma unroll
    for (int i = 0; i < 4; ++i) {
      const int m = n0 + m0 + lc*4 + i;
      if (m < NN) h[(size_t)m*DD + nt*16 + lr] = fmaxf(acc[nt][i] + bb, 0.f);
    }
  }
}

// ---- fused scan2+scan3: each block sums part[0..b-1] itself, then applies ---
__global__ __launch_bounds__(256) void k_scan23(int* __restrict__ rp,
                                                const int* __restrict__ part,
                                                int* __restrict__ fill) {
  __shared__ int ls[256];
  const int t = threadIdx.x;
  const int bb = blockIdx.x;
  int s = 0;
  for (int i = t; i < bb; i += 256) s += part[i];
  ls[t] = s; __syncthreads();
  #pragma unroll
  for (int off = 128; off > 0; off >>= 1) {
    if (t < off) ls[t] += ls[t + off];
    __syncthreads();
  }
  const int off0 = ls[0];
  const int base = bb * SB + t * 4;
  #pragma unroll
  for (int i = 0; i < 4; ++i)
    if (base + i < NR) {
      const int r = rp[base + i] + off0;
      rp[base + i] = r;
      fill[base + i] = r;
    }
  if (bb == 0 && t == 0) rp[NR] = EE;
}

__global__ void k_reorder(const int* __restrict__ ei, const float* __restrict__ ea,
                          int* __restrict__ fill, unsigned short* __restrict__ eidx) {
  const int e = blockIdx.x * 256 + threadIdx.x;
  if (e >= EE) return;
  const int key = (int)ea[2*e + 1] * NN + ei[EE + e];
  const int pos = atomicAdd(&fill[key], 1);
  eidx[pos] = (unsigned short)ei[e];
}

// ---------------- fused per-layer kernel (R6 verbatim — best known) ----------
// K-split wave parallelism: 32 dst / block, 256 threads = 4 waves = 2 dst-tiles
// x 2 K-half waves. Wave (pair, half) gathers relations half*4..half*4+3
// (half 0 also does the root term) for dst rows [pair*16, pair*16+16) into its
// PRIVATE f32 LDS staging buffer, and accumulates a private partial C over its
// K-slices -> waves are fully independent, NO barriers in the main loop.
__global__ __launch_bounds__(256, 4) void k_layer(
    const float* __restrict__ h, const unsigned short* __restrict__ eidx,
    const int* __restrict__ rp, const short* __restrict__ Btp,
    const float* __restrict__ bias, float* __restrict__ outh) {
  __shared__ float Af[4][16 * ASF];        // 4 x 4,352 B = 17,408 B
  __shared__ unsigned short els[ECAP];     // 2,048 B
  __shared__ int rpls[RR][33];             // 1,056 B
  __shared__ int baseL[RR + 1];

  const int t = threadIdx.x;
  const int lane = t & 63, wv = t >> 6;
  const int pair = wv >> 1, half = wv & 1;
  const int lr = lane & 15, lc = lane >> 4;
  const int n0 = blockIdx.x * 32;
  const int j0 = pair * 16;                // local dst-row base of this wave
  const float* hl = h + lane;

  for (int i = t; i < RR * 33; i += 256) {
    const int kk = i / 33, j = i - kk * 33;
    int g = n0 + j; if (g > NN) g = NN;
    rpls[kk][j] = rp[kk * NN + g];
  }
  __syncthreads();
  if (t == 0) {
    int s = 0;
    #pragma unroll
    for (int k = 0; k < RR; ++k) { baseL[k] = s; s += rpls[k][32] - rpls[k][0]; }
    baseL[RR] = s;
  }
  __syncthreads();
  const bool fit = baseL[RR] <= ECAP;
  if (fit) {
    for (int k = 0; k < RR; ++k) {
      const int g0 = rpls[k][0], sp = rpls[k][32] - g0, b0 = baseL[k];
      for (int i = t; i < sp; i += 256) els[b0 + i] = eidx[g0 + i];
    }
  }
  __syncthreads();

  float* Aw = Af[wv];                      // this wave's private staging

  auto gather = [&](int kk) {              // R3-proven scan structure
    const int ebeg = rpls[kk][j0], eend = rpls[kk][j0 + 16];
    int j = j0;
    int nxt = rpls[kk][j0 + 1];
    float acc = 0.f;
    auto flush = [&]() {
      const int cnt = nxt - rpls[kk][j];
      float m = (cnt > 1) ? acc * (1.0f / (float)cnt) : acc;
      Aw[(j - j0) * ASF + lane] = m;
    };
    auto proc = [&](float v, int e2) {
      while (e2 >= nxt) { flush(); acc = 0.f; ++j; nxt = rpls[kk][j + 1]; }
      acc += v;
    };
    auto scan = [&](auto srcAt) {
      int e = ebeg;
      for (; e + 15 < eend; e += 16) {   // 16 independent h-row loads in flight
        int s[16]; float v[16];
        #pragma unroll
        for (int i = 0; i < 16; ++i) s[i] = srcAt(e + i);
        #pragma unroll
        for (int i = 0; i < 16; ++i) v[i] = hl[(size_t)s[i] * DD];
        #pragma unroll
        for (int i = 0; i < 16; ++i) proc(v[i], e + i);
      }
      if (e + 7 < eend) {
        int s[8]; float v[8];
        #pragma unroll
        for (int i = 0; i < 8; ++i) s[i] = srcAt(e + i);
        #pragma unroll
        for (int i = 0; i < 8; ++i) v[i] = hl[(size_t)s[i] * DD];
        #pragma unroll
        for (int i = 0; i < 8; ++i) proc(v[i], e + i);
        e += 8;
      }
      for (; e < eend; ++e) proc(hl[(size_t)srcAt(e) * DD], e);
    };
    if (fit) {
      const int lb2 = baseL[kk] - rpls[kk][0];
      scan([&](int e) { return (int)els[lb2 + e]; });
    } else {
      scan([&](int e) { return (int)eidx[e]; });
    }
    while (true) {                       // flush current + remaining nodes
      flush();
      acc = 0.f; ++j;
      if (j >= j0 + 16) break;
      nxt = rpls[kk][j + 1];
    }
  };
  auto root_stage = [&]() {
    for (int jj = 0; jj < 16; jj += 4) {
      float v[4];
      #pragma unroll
      for (int i = 0; i < 4; ++i) {
        const int n = n0 + j0 + jj + i;
        v[i] = (n < NN) ? h[(size_t)n * DD + lane] : 0.f;
      }
      #pragma unroll
      for (int i = 0; i < 4; ++i) Aw[(jj + i) * ASF + lane] = v[i];
    }
  };

  f32x4 acc4[4];
  #pragma unroll
  for (int nt = 0; nt < 4; ++nt) acc4[nt] = (f32x4){0.f,0.f,0.f,0.f};
  int boff[4];
  #pragma unroll
  for (int nt = 0; nt < 4; ++nt) boff[nt] = (nt*16 + lr)*KB + lc*8;
  const short* Blo = Btp + (size_t)DD * KB;
  const float* arow = Aw + lr * ASF + lc * 8;

  auto mfma_slice = [&](int koff) {
    #pragma unroll
    for (int ks = 0; ks < 2; ++ks) {
      const f32x4 a0 = *(const f32x4*)(arow + ks*32);
      const f32x4 a1 = *(const f32x4*)(arow + ks*32 + 4);
      bf16x8 ah, al;
      #pragma unroll
      for (int i = 0; i < 4; ++i) {
        short hb, lb;
        split_bf(a0[i], hb, lb); ah[i] = hb;     al[i] = lb;
        split_bf(a1[i], hb, lb); ah[4 + i] = hb; al[4 + i] = lb;
      }
      #pragma unroll
      for (int nt = 0; nt < 4; ++nt) {
        const bf16x8 bh = *(const bf16x8*)(Btp + boff[nt] + koff + ks*32);
        const bf16x8 bl = *(const bf16x8*)(Blo + boff[nt] + koff + ks*32);
        acc4[nt] = __builtin_amdgcn_mfma_f32_16x16x32_bf16(ah, bh, acc4[nt], 0, 0, 0);
        acc4[nt] = __builtin_amdgcn_mfma_f32_16x16x32_bf16(al, bh, acc4[nt], 0, 0, 0);
        acc4[nt] = __builtin_amdgcn_mfma_f32_16x16x32_bf16(ah, bl, acc4[nt], 0, 0, 0);
      }
    }
  };

  // main loop: 4 relations for this K-half; no barriers (private buffers)
  #pragma unroll 1
  for (int kx = 0; kx < 4; ++kx) {
    const int kk = half * 4 + kx;
    gather(kk);
    mfma_slice(kk * 64);
  }
  if (!half) {            // half 0 also handles the root term (K 512..575)
    root_stage();
    mfma_slice(512);
  } else {                // half 1 publishes its partial C into its buffer
    #pragma unroll
    for (int nt = 0; nt < 4; ++nt)
      #pragma unroll
      for (int i = 0; i < 4; ++i)
        Aw[(lc*4 + i) * ASF + nt*16 + lr] = acc4[nt][i];
  }
  __syncthreads();        // partials visible
  if (!half) {
    const float* Pw = Af[wv + 1];
    #pragma unroll
    for (int nt = 0; nt < 4; ++nt) {
      const float bb = bias[nt*16 + lr];
      #pragma unroll
      for (int i = 0; i < 4; ++i) {
        const int m = n0 + j0 + lc*4 + i;
        if (m < NN)
          outh[(size_t)m*DD + nt*16 + lr] =
              fmaxf(acc4[nt][i] + Pw[(lc*4 + i) * ASF + nt*16 + lr] + bb, 0.f);
      }
    }
  }
}

extern "C" void kernel_launch(void* const* d_in, const int* in_sizes, int n_in,
                              void* d_out, int out_size, void* d_ws, size_t ws_size,
                              hipStream_t stream) {
  const float* x      = (const float*)d_in[0];
  const int*   ei     = (const int*)d_in[1];
  const float* ea     = (const float*)d_in[2];
  const float* W_in   = (const float*)d_in[3];
  const float* b_in   = (const float*)d_in[4];
  const float* W_rel  = (const float*)d_in[5];
  const float* W_root = (const float*)d_in[6];
  const float* b_conv = (const float*)d_in[7];
  float* out = (float*)d_out;

  // ws layout (~30.9 MB) — R6 layout, f32 h carrier
  char* ws = (char*)d_ws;
  float*          hA   = (float*)(ws);                       // 12,800,000
  float*          hB   = (float*)(ws + 12800000);            // 12,800,000
  int*            rp   = (int*)  (ws + 25600000);            // 1,600,256
  int*            fill = (int*)  (ws + 27200256);            // 1,600,000
  unsigned short* eidx = (unsigned short*)(ws + 28800256);   // 1,600,000
  int*            part = (int*)  (ws + 30400256);            // 2,048
  short*          Btp  = (short*)(ws + 30402304);            // 442,368
  short*          Wt   = (short*)(ws + 30844672);            // 32,768

  hipMemsetAsync(rp, 0, (size_t)NR*4, stream);
  // launch 2: CSR histogram (+edist out) fused with weight prep
  k_hist_prep<<<HB + PB, 256, 0, stream>>>(ei, ea, rp, out + (size_t)ND,
                                           W_rel, W_root, W_in, Btp, Wt);
  // launch 3: input projection (needs Wt) fused with scan1 (needs hist)
  k_input_scan1<<<IB + NSB, 256, 0, stream>>>(x, Wt, b_in, hA, rp, part);
  // launch 4: scan2+scan3 fused (per-block prefix over part[])
  k_scan23<<<NSB, 256, 0, stream>>>(rp, part, fill);
  // launch 5: reorder edges into CSR order
  k_reorder<<<HB, 256, 0, stream>>>(ei, ea, fill, eidx);

  const int NBL = (NN + 31) / 32;   // 1563
  k_layer<<<NBL, 256, 0, stream>>>(hA, eidx, rp,
      Btp + (size_t)0*2*DD*KB, b_conv + (size_t)0*DD, hB);
  k_layer<<<NBL, 256, 0, stream>>>(hB, eidx, rp,
      Btp + (size_t)1*2*DD*KB, b_conv + (size_t)1*DD, hA);
  k_layer<<<NBL, 256, 0, stream>>>(hA, eidx, rp,
      Btp + (size_t)2*2*DD*KB, b_conv + (size_t)2*DD, out);
}